// Round 2
// baseline (499.514 us; speedup 1.0000x reference)
//
#include <hip/hip_runtime.h>
#include <math.h>

#define SEQ    2048
#define DIMM   512
#define SH     128
#define EXP    1024
#define PROJ_  2176
#define NBATCH 8
#define ROWS   16384  // NBATCH*SEQ

typedef __attribute__((ext_vector_type(8))) short   short8;
typedef __attribute__((ext_vector_type(4))) float   floatx4;

__device__ __forceinline__ unsigned short f2bf(float f) {
  union { float f; unsigned int u; } v; v.f = f;
  unsigned int r = (v.u + 0x7fffu + ((v.u >> 16) & 1u)) >> 16;
  return (unsigned short)r;
}
__device__ __forceinline__ float bf2f(unsigned short h) {
  union { unsigned int u; float f; } v; v.u = ((unsigned int)h) << 16;
  return v.f;
}

__device__ __forceinline__ void async16(const unsigned short* g, unsigned short* l) {
  __builtin_amdgcn_global_load_lds(
      (const __attribute__((address_space(1))) void*)g,
      (__attribute__((address_space(3))) void*)l, 16, 0, 0);
}

// ---------------- RMSNorm: x (fp32, row=512) -> xn (bf16) ----------------
struct __align__(8) US4 { unsigned short a, b, c, d; };

__global__ void rmsnorm_kernel(const float* __restrict__ x, const float* __restrict__ ns,
                               unsigned short* __restrict__ xn) {
  int wave = threadIdx.x >> 6, lane = threadIdx.x & 63;
  long row = (long)blockIdx.x * 4 + wave;
  const float4* xr = (const float4*)(x + row * DIMM);
  float4 v0 = xr[lane], v1 = xr[lane + 64];
  float ss = v0.x*v0.x + v0.y*v0.y + v0.z*v0.z + v0.w*v0.w
           + v1.x*v1.x + v1.y*v1.y + v1.z*v1.z + v1.w*v1.w;
  #pragma unroll
  for (int o = 32; o > 0; o >>= 1) ss += __shfl_xor(ss, o);
  float sc = rsqrtf(ss * (1.0f / DIMM) + 1e-6f) * ns[0];
  US4 w0 = { f2bf(v0.x*sc), f2bf(v0.y*sc), f2bf(v0.z*sc), f2bf(v0.w*sc) };
  US4 w1 = { f2bf(v1.x*sc), f2bf(v1.y*sc), f2bf(v1.z*sc), f2bf(v1.w*sc) };
  ((US4*)(xn + row * DIMM))[lane]      = w0;
  ((US4*)(xn + row * DIMM))[lane + 64] = w1;
}

// ------------- transpose + fp32->bf16: in (R x C) -> out (C x R) -------------
__global__ void transpose_cvt(const float* __restrict__ in, unsigned short* __restrict__ out,
                              int R, int C) {
  __shared__ float tile[32][33];
  int c0 = blockIdx.x * 32, r0 = blockIdx.y * 32;
  #pragma unroll
  for (int j = 0; j < 32; j += 8)
    tile[threadIdx.y + j][threadIdx.x] = in[(long)(r0 + threadIdx.y + j) * C + c0 + threadIdx.x];
  __syncthreads();
  #pragma unroll
  for (int j = 0; j < 32; j += 8)
    out[(long)(c0 + threadIdx.y + j) * R + r0 + threadIdx.x] = f2bf(tile[threadIdx.x][threadIdx.y + j]);
}

// ------------- Toeplitz RoPE table: t(d), d = n - m in [-2047, 2047] -------------
__global__ void toeplitz_kernel(const float* __restrict__ a, const float* __restrict__ b,
                                float* __restrict__ tpl) {
  const int d = (int)blockIdx.x - 2047;
  const int tid = threadIdx.x;
  float sum = 0.0f;
  for (int k = tid; k < 1024; k += 256) {
    float a1 = a[k], a2 = a[k + 1024];
    float b1v = b[k], b2v = b[k + 1024];
    float p = a1 * b1v + a2 * b2v;
    float q = a1 * b2v - a2 * b1v;
    float th = powf(10000.0f, -(float)k * (1.0f / 1024.0f));
    float ang = (float)d * th;
    sum += p * cosf(ang) + q * sinf(ang);
  }
  #pragma unroll
  for (int o = 32; o > 0; o >>= 1) sum += __shfl_xor(sum, o);
  __shared__ float red[4];
  int wave = tid >> 6, lane = tid & 63;
  if (lane == 0) red[wave] = sum;
  __syncthreads();
  if (tid == 0) tpl[blockIdx.x] = red[0] + red[1] + red[2] + red[3];
}

// ======================= pipelined MFMA core =======================
// A, B row-major bf16, leading dim K (K % 128 == 0).
// 2-stage double buffer, one __syncthreads per half-iter; stage of tile i+1
// issued right after the barrier so its flight overlaps compute of tile i.
// Static buffer offsets (unroll-by-2) so AA can disambiguate LDS ranges.

__device__ __forceinline__ void stage_tile(const unsigned short* __restrict__ A,
                                           const unsigned short* __restrict__ B,
                                           int K, long rowBase, long colBase, int k0,
                                           unsigned short* As, unsigned short* Bs) {
  const int wave = threadIdx.x >> 6, lane = threadIdx.x & 63;
  const int r_l = lane >> 3, c8 = lane & 7;
  #pragma unroll
  for (int j = 0; j < 4; ++j) {
    int row = j * 32 + wave * 8 + r_l;
    int g = c8 ^ (row & 7);  // XOR-swizzled granule
    async16(A + (rowBase + row) * (long)K + k0 + g * 8, As + (j * 32 + wave * 8) * 64);
    async16(B + (colBase + row) * (long)K + k0 + g * 8, Bs + (j * 32 + wave * 8) * 64);
  }
}

__device__ __forceinline__ void compute_tile(const unsigned short* As, const unsigned short* Bs,
                                             floatx4 acc[4][4]) {
  const int lane = threadIdx.x & 63, wave = threadIdx.x >> 6;
  const int wr = (wave >> 1) * 64, wc = (wave & 1) * 64;
  const int fm = lane & 15, fq = lane >> 4;
  #pragma unroll
  for (int ks = 0; ks < 2; ++ks) {
    short8 af[4], bfr[4];
    #pragma unroll
    for (int mi = 0; mi < 4; ++mi) {
      int row = wr + mi * 16 + fm;
      int gL = (ks * 4 + fq) ^ (row & 7);
      af[mi] = *(const short8*)(As + row * 64 + gL * 8);
    }
    #pragma unroll
    for (int ni = 0; ni < 4; ++ni) {
      int row = wc + ni * 16 + fm;
      int gL = (ks * 4 + fq) ^ (row & 7);
      bfr[ni] = *(const short8*)(Bs + row * 64 + gL * 8);
    }
    #pragma unroll
    for (int mi = 0; mi < 4; ++mi)
      #pragma unroll
      for (int ni = 0; ni < 4; ++ni)
        acc[mi][ni] = __builtin_amdgcn_mfma_f32_16x16x32_bf16(af[mi], bfr[ni], acc[mi][ni], 0, 0, 0);
  }
}

#define TILE_SHORTS (128 * 64)

__device__ __forceinline__ void mfma_pipe(const unsigned short* __restrict__ A,
                                          const unsigned short* __restrict__ B,
                                          int K, long rowBase, long colBase,
                                          unsigned short* smem, floatx4 acc[4][4]) {
  unsigned short* A0 = smem;
  unsigned short* B0 = smem + TILE_SHORTS;
  unsigned short* A1 = smem + 2 * TILE_SHORTS;
  unsigned short* B1 = smem + 3 * TILE_SHORTS;

  floatx4 z = {0.0f, 0.0f, 0.0f, 0.0f};
  #pragma unroll
  for (int mi = 0; mi < 4; ++mi)
    #pragma unroll
    for (int ni = 0; ni < 4; ++ni) acc[mi][ni] = z;

  const int nIter = K >> 6;  // K % 128 == 0 -> even
  stage_tile(A, B, K, rowBase, colBase, 0, A0, B0);
  for (int it = 0; it < nIter; it += 2) {
    int k0 = it << 6;
    __syncthreads();  // implicit vmcnt(0): waits stage(it) only; stage(it+1) not yet issued
    if (it + 1 < nIter) stage_tile(A, B, K, rowBase, colBase, k0 + 64, A1, B1);
    compute_tile(A0, B0, acc);
    __syncthreads();  // waits stage(it+1); all waves done reading A0/B0
    if (it + 2 < nIter) stage_tile(A, B, K, rowBase, colBase, k0 + 128, A0, B0);
    compute_tile(A1, B1, acc);
  }
}

#define EPILOGUE_VARS                                         \
  const int lane = threadIdx.x & 63, wave = threadIdx.x >> 6; \
  const int wr = (wave >> 1) * 64, wc = (wave & 1) * 64;      \
  const int fr = (lane >> 4) * 4, fc = lane & 15;

// ------------- GEMM1: uv = swish(xn @ W1 + b1); split into u, vT, q, k -------------
__global__ void gemm_uv(const unsigned short* __restrict__ xn,
                        const unsigned short* __restrict__ w1t,
                        const float* __restrict__ b1,
                        const float* __restrict__ gamma,
                        const float* __restrict__ beta,
                        unsigned short* __restrict__ u,
                        unsigned short* __restrict__ vT,
                        unsigned short* __restrict__ qb,
                        unsigned short* __restrict__ kb) {
  __shared__ __align__(16) unsigned short smem[4 * TILE_SHORTS];
  floatx4 acc[4][4];
  long rowBase = (long)blockIdx.x * 128;
  long colBase = (long)blockIdx.y * 128;
  mfma_pipe(xn, w1t, DIMM, rowBase, colBase, smem, acc);
  EPILOGUE_VARS

  if (blockIdx.y < 8) {
    // ---- u region: direct stores ----
    #pragma unroll
    for (int mi = 0; mi < 4; ++mi)
    #pragma unroll
    for (int ni = 0; ni < 4; ++ni)
    #pragma unroll
    for (int i = 0; i < 4; ++i) {
      long row = rowBase + wr + mi * 16 + fr + i;
      long col = colBase + wc + ni * 16 + fc;
      float t = acc[mi][ni][i] + b1[col];
      u[row * EXP + col] = f2bf(t / (1.0f + __expf(-t)));
    }
  } else if (blockIdx.y < 16) {
    // ---- v region: LDS transpose -> coalesced 16B stores into vT ----
    __syncthreads();  // all waves done with staging buffers
    #pragma unroll
    for (int mi = 0; mi < 4; ++mi)
    #pragma unroll
    for (int ni = 0; ni < 4; ++ni)
    #pragma unroll
    for (int i = 0; i < 4; ++i) {
      int rl = wr + mi * 16 + fr + i;     // n-local
      int cl = wc + ni * 16 + fc;         // e-local
      long col = colBase + cl;
      float t = acc[mi][ni][i] + b1[col];
      smem[cl * 136 + rl] = f2bf(t / (1.0f + __expf(-t)));  // pitch 136: conflict-free
    }
    __syncthreads();
    long b_   = rowBase >> 11;
    long nblk = rowBase & 2047;
    long e0   = colBase - EXP;
    #pragma unroll
    for (int rep = 0; rep < 8; ++rep) {
      int cl = rep * 16 + (threadIdx.x >> 4);
      int n0 = (threadIdx.x & 15) * 8;
      short8 v8 = *(const short8*)(smem + cl * 136 + n0);
      *(short8*)(vT + (b_ * EXP + e0 + cl) * (long)SEQ + nblk + n0) = v8;
    }
  } else {
    // ---- q/k region (one col-block) ----
    #pragma unroll
    for (int mi = 0; mi < 4; ++mi)
    #pragma unroll
    for (int ni = 0; ni < 4; ++ni)
    #pragma unroll
    for (int i = 0; i < 4; ++i) {
      long row = rowBase + wr + mi * 16 + fr + i;
      long col = colBase + wc + ni * 16 + fc;
      float t = acc[mi][ni][i] + b1[col];
      float s = t / (1.0f + __expf(-t));
      int dd = (int)(col - 2 * EXP);
      qb[row * SH + dd] = f2bf(s * gamma[dd] + beta[dd]);
      kb[row * SH + dd] = f2bf(s * gamma[SH + dd] + beta[SH + dd]);
    }
  }
}

// ------------- QK: ker = relu(q.k^T/2048 + t(n-m))^2, per batch -------------
__global__ void gemm_qk(const unsigned short* __restrict__ qb,
                        const unsigned short* __restrict__ kb,
                        const float* __restrict__ tpl,
                        unsigned short* __restrict__ ker) {
  __shared__ __align__(16) unsigned short smem[4 * TILE_SHORTS];
  floatx4 acc[4][4];
  long b = blockIdx.z;
  long rowBase = (long)blockIdx.x * 128;
  long colBase = (long)blockIdx.y * 128;
  mfma_pipe(qb + b * SEQ * SH, kb + b * SEQ * SH, SH, rowBase, colBase, smem, acc);
  unsigned short* kerb = ker + b * SEQ * SEQ;
  EPILOGUE_VARS
  #pragma unroll
  for (int mi = 0; mi < 4; ++mi)
  #pragma unroll
  for (int ni = 0; ni < 4; ++ni)
  #pragma unroll
  for (int i = 0; i < 4; ++i) {
    long row = rowBase + wr + mi * 16 + fr + i;   // n
    long col = colBase + wc + ni * 16 + fc;       // m
    float val = acc[mi][ni][i] * (1.0f / 2048.0f) + tpl[row - col + 2047];
    float r = fmaxf(val, 0.0f);
    kerb[row * SEQ + col] = f2bf(r * r);
  }
}

// ------------- PV: o = (ker @ v) * u, per batch (v pre-transposed) -------------
__global__ void gemm_pv(const unsigned short* __restrict__ ker,
                        const unsigned short* __restrict__ vT,
                        const unsigned short* __restrict__ u,
                        unsigned short* __restrict__ ob) {
  __shared__ __align__(16) unsigned short smem[4 * TILE_SHORTS];
  floatx4 acc[4][4];
  long b = blockIdx.z;
  long rowBase = (long)blockIdx.x * 128;
  long colBase = (long)blockIdx.y * 128;
  mfma_pipe(ker + b * SEQ * SEQ, vT + b * EXP * SEQ, SEQ, rowBase, colBase, smem, acc);
  const unsigned short* ub = u + b * SEQ * EXP;
  unsigned short* obb = ob + b * SEQ * EXP;
  EPILOGUE_VARS
  #pragma unroll
  for (int mi = 0; mi < 4; ++mi)
  #pragma unroll
  for (int ni = 0; ni < 4; ++ni)
  #pragma unroll
  for (int i = 0; i < 4; ++i) {
    long row = rowBase + wr + mi * 16 + fr + i;   // n (within batch)
    long col = colBase + wc + ni * 16 + fc;       // e
    float val = acc[mi][ni][i] * bf2f(ub[row * EXP + col]);
    obb[row * EXP + col] = f2bf(val);
  }
}

// ------------- OUT: out = o @ W2 + b2 + x -------------
__global__ void gemm_out(const unsigned short* __restrict__ ob,
                         const unsigned short* __restrict__ w2t,
                         const float* __restrict__ b2,
                         const float* __restrict__ x,
                         float* __restrict__ out) {
  __shared__ __align__(16) unsigned short smem[4 * TILE_SHORTS];
  floatx4 acc[4][4];
  long rowBase = (long)blockIdx.x * 128;
  long colBase = (long)blockIdx.y * 128;
  mfma_pipe(ob, w2t, EXP, rowBase, colBase, smem, acc);
  EPILOGUE_VARS
  #pragma unroll
  for (int mi = 0; mi < 4; ++mi)
  #pragma unroll
  for (int ni = 0; ni < 4; ++ni)
  #pragma unroll
  for (int i = 0; i < 4; ++i) {
    long row = rowBase + wr + mi * 16 + fr + i;
    long col = colBase + wc + ni * 16 + fc;
    out[row * DIMM + col] = acc[mi][ni][i] + b2[col] + x[row * DIMM + col];
  }
}

extern "C" void kernel_launch(void* const* d_in, const int* in_sizes, int n_in,
                              void* d_out, int out_size, void* d_ws, size_t ws_size,
                              hipStream_t stream) {
  const float* x          = (const float*)d_in[0];
  const float* W1         = (const float*)d_in[1];
  const float* b1         = (const float*)d_in[2];
  const float* W2         = (const float*)d_in[3];
  const float* b2         = (const float*)d_in[4];
  const float* rope_a     = (const float*)d_in[5];
  const float* rope_b     = (const float*)d_in[6];
  const float* gamma      = (const float*)d_in[7];
  const float* beta       = (const float*)d_in[8];
  const float* norm_scale = (const float*)d_in[9];
  float* out = (float*)d_out;

  char* ws = (char*)d_ws;
  size_t off = 0;
  auto nxt = [&](size_t bytes) -> void* {
    void* p = ws + off;
    off += (bytes + 255) & ~(size_t)255;
    return p;
  };
  unsigned short* xn  = (unsigned short*)nxt((size_t)ROWS * DIMM * 2);
  unsigned short* w1t = (unsigned short*)nxt((size_t)PROJ_ * DIMM * 2);
  unsigned short* w2t = (unsigned short*)nxt((size_t)DIMM * EXP * 2);
  unsigned short* u   = (unsigned short*)nxt((size_t)ROWS * EXP * 2);
  unsigned short* vT  = (unsigned short*)nxt((size_t)NBATCH * EXP * SEQ * 2);
  unsigned short* qb  = (unsigned short*)nxt((size_t)ROWS * SH * 2);
  unsigned short* kb  = (unsigned short*)nxt((size_t)ROWS * SH * 2);
  float*          tpl = (float*)nxt((size_t)4096 * 4);
  unsigned short* ker = (unsigned short*)nxt((size_t)NBATCH * SEQ * SEQ * 2);
  unsigned short* ob  = (unsigned short*)nxt((size_t)ROWS * EXP * 2);

  rmsnorm_kernel<<<ROWS / 4, 256, 0, stream>>>(x, norm_scale, xn);
  transpose_cvt<<<dim3(PROJ_ / 32, DIMM / 32), dim3(32, 8), 0, stream>>>(W1, w1t, DIMM, PROJ_);
  transpose_cvt<<<dim3(DIMM / 32, EXP / 32), dim3(32, 8), 0, stream>>>(W2, w2t, EXP, DIMM);
  toeplitz_kernel<<<4095, 256, 0, stream>>>(rope_a, rope_b, tpl);
  gemm_uv<<<dim3(ROWS / 128, PROJ_ / 128), 256, 0, stream>>>(xn, w1t, b1, gamma, beta, u, vT, qb, kb);
  gemm_qk<<<dim3(SEQ / 128, SEQ / 128, NBATCH), 256, 0, stream>>>(qb, kb, tpl, ker);
  gemm_pv<<<dim3(SEQ / 128, EXP / 128, NBATCH), 256, 0, stream>>>(ker, vT, u, ob);
  gemm_out<<<dim3(ROWS / 128, DIMM / 128), 256, 0, stream>>>(ob, w2t, b2, x, out);
}

// Round 3
// 285.555 us; speedup vs baseline: 1.7493x; 1.7493x over previous
//
#include <hip/hip_runtime.h>
#include <math.h>

#define SEQ    2048
#define DIMM   512
#define SH     128
#define EXP    1024
#define PROJ_  2176
#define NBATCH 8
#define ROWS   16384  // NBATCH*SEQ

#define KER_SCALE     16384.0f
#define KER_SCALE_INV (1.0f / 16384.0f)

typedef __attribute__((ext_vector_type(8))) short   short8;
typedef __attribute__((ext_vector_type(4))) float   floatx4;

__device__ __forceinline__ unsigned short f2bf(float f) {
  union { float f; unsigned int u; } v; v.f = f;
  unsigned int r = (v.u + 0x7fffu + ((v.u >> 16) & 1u)) >> 16;
  return (unsigned short)r;
}
__device__ __forceinline__ float bf2f(unsigned short h) {
  union { unsigned int u; float f; } v; v.u = ((unsigned int)h) << 16;
  return v.f;
}

__device__ __forceinline__ void async16(const void* g, void* l) {
  __builtin_amdgcn_global_load_lds(
      (const __attribute__((address_space(1))) void*)g,
      (__attribute__((address_space(3))) void*)l, 16, 0, 0);
}

// =================== fused prep: rmsnorm + toeplitz + weight transposes ===================
__device__ __forceinline__ void transpose_tile(const float* __restrict__ in,
                                               unsigned short* __restrict__ out,
                                               int R, int C, int bx, int by, float* tile) {
  int tx = threadIdx.x & 31, ty = threadIdx.x >> 5;  // 32 x 8
  int c0 = bx * 32, r0 = by * 32;
  #pragma unroll
  for (int j = 0; j < 32; j += 8)
    tile[(ty + j) * 33 + tx] = in[(long)(r0 + ty + j) * C + c0 + tx];
  __syncthreads();
  #pragma unroll
  for (int j = 0; j < 32; j += 8)
    out[(long)(c0 + ty + j) * R + r0 + tx] = f2bf(tile[tx * 33 + ty + j]);
}

struct __align__(8) US4 { unsigned short a, b, c, d; };

__global__ void prep_kernel(const float* __restrict__ x, const float* __restrict__ ns,
                            unsigned short* __restrict__ xn,
                            const float* __restrict__ W1, unsigned short* __restrict__ w1t,
                            const float* __restrict__ W2, unsigned short* __restrict__ w2t,
                            const float* __restrict__ ra, const float* __restrict__ rb,
                            float* __restrict__ tpl) {
  __shared__ float sh[33 * 32];
  const int b = blockIdx.x, tid = threadIdx.x;
  if (b < 4096) {
    // ---- RMSNorm: 4 rows per block ----
    int wave = tid >> 6, lane = tid & 63;
    long row = (long)b * 4 + wave;
    const float4* xr = (const float4*)(x + row * DIMM);
    float4 v0 = xr[lane], v1 = xr[lane + 64];
    float ss = v0.x*v0.x + v0.y*v0.y + v0.z*v0.z + v0.w*v0.w
             + v1.x*v1.x + v1.y*v1.y + v1.z*v1.z + v1.w*v1.w;
    #pragma unroll
    for (int o = 32; o > 0; o >>= 1) ss += __shfl_xor(ss, o);
    float sc = rsqrtf(ss * (1.0f / DIMM) + 1e-6f) * ns[0];
    US4 w0 = { f2bf(v0.x*sc), f2bf(v0.y*sc), f2bf(v0.z*sc), f2bf(v0.w*sc) };
    US4 w1 = { f2bf(v1.x*sc), f2bf(v1.y*sc), f2bf(v1.z*sc), f2bf(v1.w*sc) };
    ((US4*)(xn + row * DIMM))[lane]      = w0;
    ((US4*)(xn + row * DIMM))[lane + 64] = w1;
  } else if (b < 4096 + 4095) {
    // ---- Toeplitz table entry d = (b-4096) - 2047 ----
    const int d = (b - 4096) - 2047;
    float sum = 0.0f;
    for (int k = tid; k < 1024; k += 256) {
      float a1 = ra[k], a2 = ra[k + 1024];
      float b1v = rb[k], b2v = rb[k + 1024];
      float p = a1 * b1v + a2 * b2v;
      float q = a1 * b2v - a2 * b1v;
      float th = powf(10000.0f, -(float)k * (1.0f / 1024.0f));
      float ang = (float)d * th;
      sum += p * cosf(ang) + q * sinf(ang);
    }
    #pragma unroll
    for (int o = 32; o > 0; o >>= 1) sum += __shfl_xor(sum, o);
    int wave = tid >> 6, lane = tid & 63;
    if (lane == 0) sh[wave] = sum;
    __syncthreads();
    if (tid == 0) tpl[b - 4096] = sh[0] + sh[1] + sh[2] + sh[3];
  } else if (b < 9279) {
    // ---- W1 (DIMM x PROJ_) -> w1t (PROJ_ x DIMM): 68 x 16 tiles ----
    int t = b - 8191;
    transpose_tile(W1, w1t, DIMM, PROJ_, t % 68, t / 68, sh);
  } else {
    // ---- W2 (EXP x DIMM) -> w2t (DIMM x EXP): 16 x 32 tiles ----
    int t = b - 9279;
    transpose_tile(W2, w2t, EXP, DIMM, t % 16, t / 16, sh);
  }
}

// =================== single-buffer bf16 MFMA core (R1) ===================
// C(128x128) = A(rowBase..,K) . B(colBase..,K)^T ; A,B row-major bf16, ld = K (K%64==0)
__device__ __forceinline__ void mfma_core(const unsigned short* __restrict__ A,
                                          const unsigned short* __restrict__ B,
                                          int K, long rowBase, long colBase,
                                          unsigned short* smem, floatx4 acc[4][4]) {
  unsigned short* As = smem;
  unsigned short* Bs = smem + 128 * 64;
  const int tid  = threadIdx.x;
  const int wave = tid >> 6;
  const int lane = tid & 63;
  const int wr   = (wave >> 1) * 64;
  const int wc   = (wave & 1) * 64;
  const int r_l  = lane >> 3;
  const int c8   = lane & 7;
  const int fm   = lane & 15;
  const int fq   = lane >> 4;

  floatx4 z = {0.0f, 0.0f, 0.0f, 0.0f};
  #pragma unroll
  for (int mi = 0; mi < 4; ++mi)
    #pragma unroll
    for (int ni = 0; ni < 4; ++ni) acc[mi][ni] = z;

  for (int k0 = 0; k0 < K; k0 += 64) {
    __syncthreads();
    #pragma unroll
    for (int j = 0; j < 4; ++j) {
      int row = j * 32 + wave * 8 + r_l;
      int g = c8 ^ (row & 7);
      async16(A + (rowBase + row) * (long)K + k0 + g * 8, As + (j * 32 + wave * 8) * 64);
      async16(B + (colBase + row) * (long)K + k0 + g * 8, Bs + (j * 32 + wave * 8) * 64);
    }
    __syncthreads();
    #pragma unroll
    for (int ks = 0; ks < 2; ++ks) {
      short8 af[4], bfr[4];
      #pragma unroll
      for (int mi = 0; mi < 4; ++mi) {
        int row = wr + mi * 16 + fm;
        int gL = (ks * 4 + fq) ^ (row & 7);
        af[mi] = *(const short8*)(As + row * 64 + gL * 8);
      }
      #pragma unroll
      for (int ni = 0; ni < 4; ++ni) {
        int row = wc + ni * 16 + fm;
        int gL = (ks * 4 + fq) ^ (row & 7);
        bfr[ni] = *(const short8*)(Bs + row * 64 + gL * 8);
      }
      #pragma unroll
      for (int mi = 0; mi < 4; ++mi)
        #pragma unroll
        for (int ni = 0; ni < 4; ++ni)
          acc[mi][ni] = __builtin_amdgcn_mfma_f32_16x16x32_bf16(af[mi], bfr[ni], acc[mi][ni], 0, 0, 0);
    }
  }
}

// =================== single-buffer fp8 (e4m3) MFMA core, BK=128 ===================
// C(128x128) = A . B^T ; A,B row-major fp8 bytes, ld = K (K%128==0)
__device__ __forceinline__ void mfma_core_fp8(const unsigned char* __restrict__ A,
                                              const unsigned char* __restrict__ B,
                                              int K, long rowBase, long colBase,
                                              unsigned char* smem, floatx4 acc[4][4]) {
  unsigned char* As = smem;
  unsigned char* Bs = smem + 128 * 128;
  const int tid  = threadIdx.x;
  const int wave = tid >> 6;
  const int lane = tid & 63;
  const int wr   = (wave >> 1) * 64;
  const int wc   = (wave & 1) * 64;
  const int r_l  = lane >> 3;   // 8 rows per wave-round (row = 128 B)
  const int c8   = lane & 7;    // 16-B granule
  const int fm   = lane & 15;
  const int fq   = lane >> 4;

  floatx4 z = {0.0f, 0.0f, 0.0f, 0.0f};
  #pragma unroll
  for (int mi = 0; mi < 4; ++mi)
    #pragma unroll
    for (int ni = 0; ni < 4; ++ni) acc[mi][ni] = z;

  for (int k0 = 0; k0 < K; k0 += 128) {
    __syncthreads();
    #pragma unroll
    for (int j = 0; j < 4; ++j) {
      int row = j * 32 + wave * 8 + r_l;
      int g = c8 ^ (row & 7);  // 8 granules of 16 B per 128-B row
      async16(A + (rowBase + row) * (long)K + k0 + g * 16, As + (j * 32 + wave * 8) * 128);
      async16(B + (colBase + row) * (long)K + k0 + g * 16, Bs + (j * 32 + wave * 8) * 128);
    }
    __syncthreads();
    #pragma unroll
    for (int ks = 0; ks < 4; ++ks) {
      long af[4], bfr[4];
      #pragma unroll
      for (int mi = 0; mi < 4; ++mi) {
        int row = wr + mi * 16 + fm;
        int g = (ks * 2 + (fq >> 1)) ^ (row & 7);
        af[mi] = *(const long*)(As + row * 128 + g * 16 + (fq & 1) * 8);
      }
      #pragma unroll
      for (int ni = 0; ni < 4; ++ni) {
        int row = wc + ni * 16 + fm;
        int g = (ks * 2 + (fq >> 1)) ^ (row & 7);
        bfr[ni] = *(const long*)(Bs + row * 128 + g * 16 + (fq & 1) * 8);
      }
      #pragma unroll
      for (int mi = 0; mi < 4; ++mi)
        #pragma unroll
        for (int ni = 0; ni < 4; ++ni)
          acc[mi][ni] = __builtin_amdgcn_mfma_f32_16x16x32_fp8_fp8(af[mi], bfr[ni], acc[mi][ni], 0, 0, 0);
    }
  }
}

#define EPILOGUE_VARS                                         \
  const int lane = threadIdx.x & 63, wave = threadIdx.x >> 6; \
  const int wr = (wave >> 1) * 64, wc = (wave & 1) * 64;      \
  const int fr = (lane >> 4) * 4, fc = lane & 15;

// ------------- GEMM1: uv = swish(xn @ W1 + b1); split into u(bf16), vT(fp8), q, k -------------
__global__ void gemm_uv(const unsigned short* __restrict__ xn,
                        const unsigned short* __restrict__ w1t,
                        const float* __restrict__ b1,
                        const float* __restrict__ gamma,
                        const float* __restrict__ beta,
                        unsigned short* __restrict__ u,
                        unsigned char* __restrict__ vT,
                        unsigned short* __restrict__ qb,
                        unsigned short* __restrict__ kb) {
  __shared__ __align__(16) unsigned short smem[128 * 136];  // core uses first 32 KB
  floatx4 acc[4][4];
  long rowBase = (long)blockIdx.x * 128;
  long colBase = (long)blockIdx.y * 128;
  mfma_core(xn, w1t, DIMM, rowBase, colBase, smem, acc);
  EPILOGUE_VARS

  if (blockIdx.y < 8) {
    #pragma unroll
    for (int mi = 0; mi < 4; ++mi)
    #pragma unroll
    for (int ni = 0; ni < 4; ++ni)
    #pragma unroll
    for (int i = 0; i < 4; ++i) {
      long row = rowBase + wr + mi * 16 + fr + i;
      long col = colBase + wc + ni * 16 + fc;
      float t = acc[mi][ni][i] + b1[col];
      u[row * EXP + col] = f2bf(t / (1.0f + __expf(-t)));
    }
  } else if (blockIdx.y < 16) {
    // v region: LDS transpose -> coalesced fp8 stores into vT
    __syncthreads();
    #pragma unroll
    for (int mi = 0; mi < 4; ++mi)
    #pragma unroll
    for (int ni = 0; ni < 4; ++ni)
    #pragma unroll
    for (int i = 0; i < 4; ++i) {
      int rl = wr + mi * 16 + fr + i;     // n-local
      int cl = wc + ni * 16 + fc;         // e-local
      long col = colBase + cl;
      float t = acc[mi][ni][i] + b1[col];
      smem[cl * 136 + rl] = f2bf(t / (1.0f + __expf(-t)));
    }
    __syncthreads();
    long b_   = rowBase >> 11;
    long nblk = rowBase & 2047;
    long e0   = colBase - EXP;
    #pragma unroll
    for (int rep = 0; rep < 8; ++rep) {
      int cl = rep * 16 + (threadIdx.x >> 4);
      int n0 = (threadIdx.x & 15) * 8;
      const unsigned short* src = smem + cl * 136 + n0;
      unsigned int w0 = __builtin_amdgcn_cvt_pk_fp8_f32(bf2f(src[0]), bf2f(src[1]), 0, false);
      w0 = __builtin_amdgcn_cvt_pk_fp8_f32(bf2f(src[2]), bf2f(src[3]), w0, true);
      unsigned int w1 = __builtin_amdgcn_cvt_pk_fp8_f32(bf2f(src[4]), bf2f(src[5]), 0, false);
      w1 = __builtin_amdgcn_cvt_pk_fp8_f32(bf2f(src[6]), bf2f(src[7]), w1, true);
      uint2 pk; pk.x = w0; pk.y = w1;
      *(uint2*)(vT + (b_ * EXP + e0 + cl) * (long)SEQ + nblk + n0) = pk;
    }
  } else {
    #pragma unroll
    for (int mi = 0; mi < 4; ++mi)
    #pragma unroll
    for (int ni = 0; ni < 4; ++ni)
    #pragma unroll
    for (int i = 0; i < 4; ++i) {
      long row = rowBase + wr + mi * 16 + fr + i;
      long col = colBase + wc + ni * 16 + fc;
      float t = acc[mi][ni][i] + b1[col];
      float s = t / (1.0f + __expf(-t));
      int dd = (int)(col - 2 * EXP);
      qb[row * SH + dd] = f2bf(s * gamma[dd] + beta[dd]);
      kb[row * SH + dd] = f2bf(s * gamma[SH + dd] + beta[SH + dd]);
    }
  }
}

// ------------- QK: ker = min(relu(q.k^T/2048 + t)^2 * 2^14, 440) in fp8 e4m3 -------------
__global__ void gemm_qk(const unsigned short* __restrict__ qb,
                        const unsigned short* __restrict__ kb,
                        const float* __restrict__ tpl,
                        unsigned char* __restrict__ ker) {
  __shared__ __align__(16) unsigned short smem[2 * 128 * 64];
  floatx4 acc[4][4];
  long b = blockIdx.z;
  long rowBase = (long)blockIdx.x * 128;
  long colBase = (long)blockIdx.y * 128;
  mfma_core(qb + b * SEQ * SH, kb + b * SEQ * SH, SH, rowBase, colBase, smem, acc);
  unsigned char* kerb = ker + b * (long)SEQ * SEQ;
  EPILOGUE_VARS
  #pragma unroll
  for (int mi = 0; mi < 4; ++mi)
  #pragma unroll
  for (int ni = 0; ni < 4; ++ni)
  #pragma unroll
  for (int i = 0; i < 4; ++i) {
    long row = rowBase + wr + mi * 16 + fr + i;   // n
    long col = colBase + wc + ni * 16 + fc;       // m
    float val = acc[mi][ni][i] * (1.0f / 2048.0f) + tpl[row - col + 2047];
    float r = fmaxf(val, 0.0f);
    float kv = fminf(r * r * KER_SCALE, 440.0f);
    kerb[row * SEQ + col] =
        (unsigned char)(__builtin_amdgcn_cvt_pk_fp8_f32(kv, 0.0f, 0, false) & 0xffu);
  }
}

// ------------- PV: o = (ker @ v) * u * 2^-14, per batch; fp8 core -------------
__global__ void gemm_pv(const unsigned char* __restrict__ ker,
                        const unsigned char* __restrict__ vT,
                        const unsigned short* __restrict__ u,
                        unsigned short* __restrict__ ob) {
  __shared__ __align__(16) unsigned char smem8[2 * 128 * 128];
  floatx4 acc[4][4];
  long b = blockIdx.z;
  long colBase = (long)blockIdx.x * 128;  // e (fastest: consecutive blocks share ker A-slice)
  long rowBase = (long)blockIdx.y * 128;  // n
  mfma_core_fp8(ker + b * (long)SEQ * SEQ, vT + b * (long)EXP * SEQ, SEQ,
                rowBase, colBase, smem8, acc);
  const unsigned short* ub = u + b * (long)SEQ * EXP;
  unsigned short* obb = ob + b * (long)SEQ * EXP;
  EPILOGUE_VARS
  #pragma unroll
  for (int mi = 0; mi < 4; ++mi)
  #pragma unroll
  for (int ni = 0; ni < 4; ++ni)
  #pragma unroll
  for (int i = 0; i < 4; ++i) {
    long row = rowBase + wr + mi * 16 + fr + i;   // n (within batch)
    long col = colBase + wc + ni * 16 + fc;       // e
    float val = acc[mi][ni][i] * KER_SCALE_INV * bf2f(ub[row * EXP + col]);
    obb[row * EXP + col] = f2bf(val);
  }
}

// ------------- OUT: out = o @ W2 + b2 + x -------------
__global__ void gemm_out(const unsigned short* __restrict__ ob,
                         const unsigned short* __restrict__ w2t,
                         const float* __restrict__ b2,
                         const float* __restrict__ x,
                         float* __restrict__ out) {
  __shared__ __align__(16) unsigned short smem[2 * 128 * 64];
  floatx4 acc[4][4];
  long rowBase = (long)blockIdx.x * 128;
  long colBase = (long)blockIdx.y * 128;
  mfma_core(ob, w2t, EXP, rowBase, colBase, smem, acc);
  EPILOGUE_VARS
  #pragma unroll
  for (int mi = 0; mi < 4; ++mi)
  #pragma unroll
  for (int ni = 0; ni < 4; ++ni)
  #pragma unroll
  for (int i = 0; i < 4; ++i) {
    long row = rowBase + wr + mi * 16 + fr + i;
    long col = colBase + wc + ni * 16 + fc;
    out[row * DIMM + col] = acc[mi][ni][i] + b2[col] + x[row * DIMM + col];
  }
}

extern "C" void kernel_launch(void* const* d_in, const int* in_sizes, int n_in,
                              void* d_out, int out_size, void* d_ws, size_t ws_size,
                              hipStream_t stream) {
  const float* x          = (const float*)d_in[0];
  const float* W1         = (const float*)d_in[1];
  const float* b1         = (const float*)d_in[2];
  const float* W2         = (const float*)d_in[3];
  const float* b2         = (const float*)d_in[4];
  const float* rope_a     = (const float*)d_in[5];
  const float* rope_b     = (const float*)d_in[6];
  const float* gamma      = (const float*)d_in[7];
  const float* beta       = (const float*)d_in[8];
  const float* norm_scale = (const float*)d_in[9];
  float* out = (float*)d_out;

  char* ws = (char*)d_ws;
  size_t off = 0;
  auto nxt = [&](size_t bytes) -> void* {
    void* p = ws + off;
    off += (bytes + 255) & ~(size_t)255;
    return p;
  };
  unsigned short* xn  = (unsigned short*)nxt((size_t)ROWS * DIMM * 2);
  unsigned short* w1t = (unsigned short*)nxt((size_t)PROJ_ * DIMM * 2);
  unsigned short* w2t = (unsigned short*)nxt((size_t)DIMM * EXP * 2);
  unsigned short* u   = (unsigned short*)nxt((size_t)ROWS * EXP * 2);
  unsigned char*  vT  = (unsigned char*)nxt((size_t)NBATCH * EXP * SEQ);
  unsigned short* qb  = (unsigned short*)nxt((size_t)ROWS * SH * 2);
  unsigned short* kb  = (unsigned short*)nxt((size_t)ROWS * SH * 2);
  float*          tpl = (float*)nxt((size_t)4096 * 4);
  unsigned char*  ker = (unsigned char*)nxt((size_t)NBATCH * SEQ * SEQ);
  unsigned short* ob  = (unsigned short*)nxt((size_t)ROWS * EXP * 2);

  prep_kernel<<<9791, 256, 0, stream>>>(x, norm_scale, xn, W1, w1t, W2, w2t,
                                        rope_a, rope_b, tpl);
  gemm_uv<<<dim3(ROWS / 128, PROJ_ / 128), 256, 0, stream>>>(xn, w1t, b1, gamma, beta,
                                                             u, vT, qb, kb);
  gemm_qk<<<dim3(SEQ / 128, SEQ / 128, NBATCH), 256, 0, stream>>>(qb, kb, tpl, ker);
  gemm_pv<<<dim3(EXP / 128, SEQ / 128, NBATCH), 256, 0, stream>>>(ker, vT, u, ob);
  gemm_out<<<dim3(ROWS / 128, DIMM / 128), 256, 0, stream>>>(ob, w2t, b2, x, out);
}

// Round 4
// 285.363 us; speedup vs baseline: 1.7504x; 1.0007x over previous
//
#include <hip/hip_runtime.h>
#include <math.h>

#define SEQ    2048
#define DIMM   512
#define SH     128
#define EXP    1024
#define PROJ_  2176
#define NBATCH 8
#define ROWS   16384  // NBATCH*SEQ

#define KER_SCALE     16384.0f
#define KER_SCALE_INV (1.0f / 16384.0f)
#define QK_INV        (1.0f / (4096.0f * 2048.0f))   // q,k scaled x64 each; /MAX_LEN
#define W8            64.0f                          // generic fp8 pre-scale
#define OUT_INV       (1.0f / 4096.0f)               // ob x64, W2 x64

typedef __attribute__((ext_vector_type(8))) short   short8;
typedef __attribute__((ext_vector_type(4))) float   floatx4;

__device__ __forceinline__ unsigned short f2bf(float f) {
  union { float f; unsigned int u; } v; v.f = f;
  unsigned int r = (v.u + 0x7fffu + ((v.u >> 16) & 1u)) >> 16;
  return (unsigned short)r;
}
__device__ __forceinline__ float bf2f(unsigned short h) {
  union { unsigned int u; float f; } v; v.u = ((unsigned int)h) << 16;
  return v.f;
}
__device__ __forceinline__ unsigned char f2fp8(float f) {
  return (unsigned char)(__builtin_amdgcn_cvt_pk_fp8_f32(f, 0.0f, 0, false) & 0xffu);
}
// manual e4m3fn decode (avoids relying on cvt_f32_fp8 builtin signature)
__device__ __forceinline__ float fp82f(unsigned char b) {
  int e = (b >> 3) & 15, m = b & 7;
  float v = ldexpf((float)(e ? (8 + m) : m), (e ? e : 1) - 10);
  return (b & 0x80) ? -v : v;
}

__device__ __forceinline__ void async16(const void* g, void* l) {
  __builtin_amdgcn_global_load_lds(
      (const __attribute__((address_space(1))) void*)g,
      (__attribute__((address_space(3))) void*)l, 16, 0, 0);
}

// =================== fused prep: rmsnorm + toeplitz + weight transposes ===================
__device__ __forceinline__ void transpose_tile_bf16(const float* __restrict__ in,
                                                    unsigned short* __restrict__ out,
                                                    int R, int C, int bx, int by, float* tile) {
  int tx = threadIdx.x & 31, ty = threadIdx.x >> 5;  // 32 x 8
  int c0 = bx * 32, r0 = by * 32;
  #pragma unroll
  for (int j = 0; j < 32; j += 8)
    tile[(ty + j) * 33 + tx] = in[(long)(r0 + ty + j) * C + c0 + tx];
  __syncthreads();
  #pragma unroll
  for (int j = 0; j < 32; j += 8)
    out[(long)(c0 + ty + j) * R + r0 + tx] = f2bf(tile[tx * 33 + ty + j]);
}

__device__ __forceinline__ void transpose_tile_fp8(const float* __restrict__ in,
                                                   unsigned char* __restrict__ out,
                                                   int R, int C, int bx, int by, float* tile) {
  int tx = threadIdx.x & 31, ty = threadIdx.x >> 5;
  int c0 = bx * 32, r0 = by * 32;
  #pragma unroll
  for (int j = 0; j < 32; j += 8)
    tile[(ty + j) * 33 + tx] = in[(long)(r0 + ty + j) * C + c0 + tx];
  __syncthreads();
  #pragma unroll
  for (int j = 0; j < 32; j += 8)
    out[(long)(c0 + ty + j) * R + r0 + tx] = f2fp8(tile[tx * 33 + ty + j] * W8);
}

struct __align__(8) US4 { unsigned short a, b, c, d; };

__global__ void prep_kernel(const float* __restrict__ x, const float* __restrict__ ns,
                            unsigned short* __restrict__ xn,
                            const float* __restrict__ W1, unsigned short* __restrict__ w1t,
                            const float* __restrict__ W2, unsigned char* __restrict__ w2q,
                            const float* __restrict__ ra, const float* __restrict__ rb,
                            float* __restrict__ tpl) {
  __shared__ float sh[33 * 32];
  const int b = blockIdx.x, tid = threadIdx.x;
  if (b < 4096) {
    // ---- RMSNorm: 4 rows per block ----
    int wave = tid >> 6, lane = tid & 63;
    long row = (long)b * 4 + wave;
    const float4* xr = (const float4*)(x + row * DIMM);
    float4 v0 = xr[lane], v1 = xr[lane + 64];
    float ss = v0.x*v0.x + v0.y*v0.y + v0.z*v0.z + v0.w*v0.w
             + v1.x*v1.x + v1.y*v1.y + v1.z*v1.z + v1.w*v1.w;
    #pragma unroll
    for (int o = 32; o > 0; o >>= 1) ss += __shfl_xor(ss, o);
    float sc = rsqrtf(ss * (1.0f / DIMM) + 1e-6f) * ns[0];
    US4 w0 = { f2bf(v0.x*sc), f2bf(v0.y*sc), f2bf(v0.z*sc), f2bf(v0.w*sc) };
    US4 w1 = { f2bf(v1.x*sc), f2bf(v1.y*sc), f2bf(v1.z*sc), f2bf(v1.w*sc) };
    ((US4*)(xn + row * DIMM))[lane]      = w0;
    ((US4*)(xn + row * DIMM))[lane + 64] = w1;
  } else if (b < 4096 + 4095) {
    // ---- Toeplitz table entry d = (b-4096) - 2047 ----
    const int d = (b - 4096) - 2047;
    float sum = 0.0f;
    for (int k = tid; k < 1024; k += 256) {
      float a1 = ra[k], a2 = ra[k + 1024];
      float b1v = rb[k], b2v = rb[k + 1024];
      float p = a1 * b1v + a2 * b2v;
      float q = a1 * b2v - a2 * b1v;
      float th = powf(10000.0f, -(float)k * (1.0f / 1024.0f));
      float ang = (float)d * th;
      sum += p * cosf(ang) + q * sinf(ang);
    }
    #pragma unroll
    for (int o = 32; o > 0; o >>= 1) sum += __shfl_xor(sum, o);
    int wave = tid >> 6, lane = tid & 63;
    if (lane == 0) sh[wave] = sum;
    __syncthreads();
    if (tid == 0) tpl[b - 4096] = sh[0] + sh[1] + sh[2] + sh[3];
  } else if (b < 9279) {
    // ---- W1 (DIMM x PROJ_) -> w1t (PROJ_ x DIMM) bf16 ----
    int t = b - 8191;
    transpose_tile_bf16(W1, w1t, DIMM, PROJ_, t % 68, t / 68, sh);
  } else {
    // ---- W2 (EXP x DIMM) -> w2q (DIMM x EXP) fp8 x64 ----
    int t = b - 9279;
    transpose_tile_fp8(W2, w2q, EXP, DIMM, t % 16, t / 16, sh);
  }
}

// =================== single-buffer bf16 MFMA core ===================
// C(128x128) = A(rowBase..,K) . B(colBase..,K)^T ; A,B row-major bf16, ld = K (K%64==0)
__device__ __forceinline__ void mfma_core(const unsigned short* __restrict__ A,
                                          const unsigned short* __restrict__ B,
                                          int K, long rowBase, long colBase,
                                          unsigned short* smem, floatx4 acc[4][4]) {
  unsigned short* As = smem;
  unsigned short* Bs = smem + 128 * 64;
  const int tid  = threadIdx.x;
  const int wave = tid >> 6;
  const int lane = tid & 63;
  const int wr   = (wave >> 1) * 64;
  const int wc   = (wave & 1) * 64;
  const int r_l  = lane >> 3;
  const int c8   = lane & 7;
  const int fm   = lane & 15;
  const int fq   = lane >> 4;

  floatx4 z = {0.0f, 0.0f, 0.0f, 0.0f};
  #pragma unroll
  for (int mi = 0; mi < 4; ++mi)
    #pragma unroll
    for (int ni = 0; ni < 4; ++ni) acc[mi][ni] = z;

  for (int k0 = 0; k0 < K; k0 += 64) {
    __syncthreads();
    #pragma unroll
    for (int j = 0; j < 4; ++j) {
      int row = j * 32 + wave * 8 + r_l;
      int g = c8 ^ (row & 7);
      async16(A + (rowBase + row) * (long)K + k0 + g * 8, As + (j * 32 + wave * 8) * 64);
      async16(B + (colBase + row) * (long)K + k0 + g * 8, Bs + (j * 32 + wave * 8) * 64);
    }
    __syncthreads();
    #pragma unroll
    for (int ks = 0; ks < 2; ++ks) {
      short8 af[4], bfr[4];
      #pragma unroll
      for (int mi = 0; mi < 4; ++mi) {
        int row = wr + mi * 16 + fm;
        int gL = (ks * 4 + fq) ^ (row & 7);
        af[mi] = *(const short8*)(As + row * 64 + gL * 8);
      }
      #pragma unroll
      for (int ni = 0; ni < 4; ++ni) {
        int row = wc + ni * 16 + fm;
        int gL = (ks * 4 + fq) ^ (row & 7);
        bfr[ni] = *(const short8*)(Bs + row * 64 + gL * 8);
      }
      #pragma unroll
      for (int mi = 0; mi < 4; ++mi)
        #pragma unroll
        for (int ni = 0; ni < 4; ++ni)
          acc[mi][ni] = __builtin_amdgcn_mfma_f32_16x16x32_bf16(af[mi], bfr[ni], acc[mi][ni], 0, 0, 0);
    }
  }
}

// =================== single-buffer fp8 (e4m3) MFMA core, BK=128 ===================
__device__ __forceinline__ void mfma_core_fp8(const unsigned char* __restrict__ A,
                                              const unsigned char* __restrict__ B,
                                              int K, long rowBase, long colBase,
                                              unsigned char* smem, floatx4 acc[4][4]) {
  unsigned char* As = smem;
  unsigned char* Bs = smem + 128 * 128;
  const int tid  = threadIdx.x;
  const int wave = tid >> 6;
  const int lane = tid & 63;
  const int wr   = (wave >> 1) * 64;
  const int wc   = (wave & 1) * 64;
  const int r_l  = lane >> 3;
  const int c8   = lane & 7;
  const int fm   = lane & 15;
  const int fq   = lane >> 4;

  floatx4 z = {0.0f, 0.0f, 0.0f, 0.0f};
  #pragma unroll
  for (int mi = 0; mi < 4; ++mi)
    #pragma unroll
    for (int ni = 0; ni < 4; ++ni) acc[mi][ni] = z;

  for (int k0 = 0; k0 < K; k0 += 128) {
    __syncthreads();
    #pragma unroll
    for (int j = 0; j < 4; ++j) {
      int row = j * 32 + wave * 8 + r_l;
      int g = c8 ^ (row & 7);
      async16(A + (rowBase + row) * (long)K + k0 + g * 16, As + (j * 32 + wave * 8) * 128);
      async16(B + (colBase + row) * (long)K + k0 + g * 16, Bs + (j * 32 + wave * 8) * 128);
    }
    __syncthreads();
    #pragma unroll
    for (int ks = 0; ks < 4; ++ks) {
      long af[4], bfr[4];
      #pragma unroll
      for (int mi = 0; mi < 4; ++mi) {
        int row = wr + mi * 16 + fm;
        int g = (ks * 2 + (fq >> 1)) ^ (row & 7);
        af[mi] = *(const long*)(As + row * 128 + g * 16 + (fq & 1) * 8);
      }
      #pragma unroll
      for (int ni = 0; ni < 4; ++ni) {
        int row = wc + ni * 16 + fm;
        int g = (ks * 2 + (fq >> 1)) ^ (row & 7);
        bfr[ni] = *(const long*)(Bs + row * 128 + g * 16 + (fq & 1) * 8);
      }
      #pragma unroll
      for (int mi = 0; mi < 4; ++mi)
        #pragma unroll
        for (int ni = 0; ni < 4; ++ni)
          acc[mi][ni] = __builtin_amdgcn_mfma_f32_16x16x32_fp8_fp8(af[mi], bfr[ni], acc[mi][ni], 0, 0, 0);
    }
  }
}

#define EPILOGUE_VARS                                         \
  const int lane = threadIdx.x & 63, wave = threadIdx.x >> 6; \
  const int wr = (wave >> 1) * 64, wc = (wave & 1) * 64;      \
  const int fr = (lane >> 4) * 4, fc = lane & 15;

// ------------- GEMM1: uv = swish(xn @ W1 + b1); split into u(fp8 x64), vT(fp8), q/k(fp8 x64) -------------
__global__ void gemm_uv(const unsigned short* __restrict__ xn,
                        const unsigned short* __restrict__ w1t,
                        const float* __restrict__ b1,
                        const float* __restrict__ gamma,
                        const float* __restrict__ beta,
                        unsigned char* __restrict__ uq,
                        unsigned char* __restrict__ vT,
                        unsigned char* __restrict__ qq,
                        unsigned char* __restrict__ kq) {
  __shared__ __align__(16) unsigned short smem[128 * 136];  // core uses first 32 KB
  floatx4 acc[4][4];
  long rowBase = (long)blockIdx.x * 128;
  long colBase = (long)blockIdx.y * 128;
  mfma_core(xn, w1t, DIMM, rowBase, colBase, smem, acc);
  EPILOGUE_VARS

  if (blockIdx.y < 8) {
    #pragma unroll
    for (int mi = 0; mi < 4; ++mi)
    #pragma unroll
    for (int ni = 0; ni < 4; ++ni)
    #pragma unroll
    for (int i = 0; i < 4; ++i) {
      long row = rowBase + wr + mi * 16 + fr + i;
      long col = colBase + wc + ni * 16 + fc;
      float t = acc[mi][ni][i] + b1[col];
      uq[row * EXP + col] = f2fp8(t / (1.0f + __expf(-t)) * W8);
    }
  } else if (blockIdx.y < 16) {
    // v region: LDS transpose -> coalesced fp8 stores into vT
    __syncthreads();
    #pragma unroll
    for (int mi = 0; mi < 4; ++mi)
    #pragma unroll
    for (int ni = 0; ni < 4; ++ni)
    #pragma unroll
    for (int i = 0; i < 4; ++i) {
      int rl = wr + mi * 16 + fr + i;     // n-local
      int cl = wc + ni * 16 + fc;         // e-local
      long col = colBase + cl;
      float t = acc[mi][ni][i] + b1[col];
      smem[cl * 136 + rl] = f2bf(t / (1.0f + __expf(-t)));
    }
    __syncthreads();
    long b_   = rowBase >> 11;
    long nblk = rowBase & 2047;
    long e0   = colBase - EXP;
    #pragma unroll
    for (int rep = 0; rep < 8; ++rep) {
      int cl = rep * 16 + (threadIdx.x >> 4);
      int n0 = (threadIdx.x & 15) * 8;
      const unsigned short* src = smem + cl * 136 + n0;
      unsigned int w0 = __builtin_amdgcn_cvt_pk_fp8_f32(bf2f(src[0]), bf2f(src[1]), 0, false);
      w0 = __builtin_amdgcn_cvt_pk_fp8_f32(bf2f(src[2]), bf2f(src[3]), w0, true);
      unsigned int w1 = __builtin_amdgcn_cvt_pk_fp8_f32(bf2f(src[4]), bf2f(src[5]), 0, false);
      w1 = __builtin_amdgcn_cvt_pk_fp8_f32(bf2f(src[6]), bf2f(src[7]), w1, true);
      uint2 pk; pk.x = w0; pk.y = w1;
      *(uint2*)(vT + (b_ * EXP + e0 + cl) * (long)SEQ + nblk + n0) = pk;
    }
  } else {
    #pragma unroll
    for (int mi = 0; mi < 4; ++mi)
    #pragma unroll
    for (int ni = 0; ni < 4; ++ni)
    #pragma unroll
    for (int i = 0; i < 4; ++i) {
      long row = rowBase + wr + mi * 16 + fr + i;
      long col = colBase + wc + ni * 16 + fc;
      float t = acc[mi][ni][i] + b1[col];
      float s = t / (1.0f + __expf(-t));
      int dd = (int)(col - 2 * EXP);
      qq[row * SH + dd] = f2fp8((s * gamma[dd] + beta[dd]) * W8);
      kq[row * SH + dd] = f2fp8((s * gamma[SH + dd] + beta[SH + dd]) * W8);
    }
  }
}

// ------------- QK: ker = min(relu(qk/2048 + t)^2 * 2^14, 440) fp8; fp8 core, one K-iter -------------
__global__ void gemm_qk(const unsigned char* __restrict__ qq,
                        const unsigned char* __restrict__ kq,
                        const float* __restrict__ tpl,
                        unsigned char* __restrict__ ker) {
  __shared__ __align__(16) unsigned char smem8[2 * 128 * 128];
  floatx4 acc[4][4];
  // XCD-aware decode: batch = L&7 (one batch per XCD)
  int L = blockIdx.x;
  long b = L & 7;
  int w = L >> 3;                 // 0..255
  long colBase = (long)(w & 15) * 128;
  long rowBase = (long)(w >> 4) * 128;
  mfma_core_fp8(qq + b * SEQ * SH, kq + b * SEQ * SH, SH, rowBase, colBase, smem8, acc);
  unsigned char* kerb = ker + b * (long)SEQ * SEQ;
  EPILOGUE_VARS
  #pragma unroll
  for (int mi = 0; mi < 4; ++mi)
  #pragma unroll
  for (int ni = 0; ni < 4; ++ni)
  #pragma unroll
  for (int i = 0; i < 4; ++i) {
    long row = rowBase + wr + mi * 16 + fr + i;   // n
    long col = colBase + wc + ni * 16 + fc;       // m
    float val = acc[mi][ni][i] * QK_INV + tpl[row - col + 2047];
    float r = fmaxf(val, 0.0f);
    float kv = fminf(r * r * KER_SCALE, 440.0f);
    kerb[row * SEQ + col] = f2fp8(kv);
  }
}

// ------------- PV: ob = (ker @ v) * u, fp8 core; ob stored fp8 x64 -------------
__global__ void gemm_pv(const unsigned char* __restrict__ ker,
                        const unsigned char* __restrict__ vT,
                        const unsigned char* __restrict__ uq,
                        unsigned char* __restrict__ obq) {
  __shared__ __align__(16) unsigned char smem8[2 * 128 * 128];
  floatx4 acc[4][4];
  // XCD-aware decode: batch = L&7; within batch e-fastest for ker slice reuse
  int L = blockIdx.x;
  long b = L & 7;
  int w = L >> 3;                 // 0..127
  long colBase = (long)(w & 7) * 128;   // e
  long rowBase = (long)(w >> 3) * 128;  // n
  mfma_core_fp8(ker + b * (long)SEQ * SEQ, vT + b * (long)EXP * SEQ, SEQ,
                rowBase, colBase, smem8, acc);
  const unsigned char* ub = uq + b * (long)SEQ * EXP;
  unsigned char* obb = obq + b * (long)SEQ * EXP;
  EPILOGUE_VARS
  #pragma unroll
  for (int mi = 0; mi < 4; ++mi)
  #pragma unroll
  for (int ni = 0; ni < 4; ++ni)
  #pragma unroll
  for (int i = 0; i < 4; ++i) {
    long row = rowBase + wr + mi * 16 + fr + i;   // n (within batch)
    long col = colBase + wc + ni * 16 + fc;       // e
    // uq holds u*64; store o*64  ->  scales cancel: acc * 2^-14 * (u*64)
    float val = acc[mi][ni][i] * KER_SCALE_INV * fp82f(ub[row * EXP + col]);
    obb[row * EXP + col] = f2fp8(val);
  }
}

// ------------- OUT: out = (ob/64) @ (W2) + b2 + x ; fp8 core, acc * 1/4096 -------------
__global__ void gemm_out(const unsigned char* __restrict__ obq,
                         const unsigned char* __restrict__ w2q,
                         const float* __restrict__ b2,
                         const float* __restrict__ x,
                         float* __restrict__ out) {
  __shared__ __align__(16) unsigned char smem8[2 * 128 * 128];
  floatx4 acc[4][4];
  long rowBase = (long)blockIdx.x * 128;
  long colBase = (long)blockIdx.y * 128;
  mfma_core_fp8(obq, w2q, EXP, rowBase, colBase, smem8, acc);
  EPILOGUE_VARS
  #pragma unroll
  for (int mi = 0; mi < 4; ++mi)
  #pragma unroll
  for (int ni = 0; ni < 4; ++ni)
  #pragma unroll
  for (int i = 0; i < 4; ++i) {
    long row = rowBase + wr + mi * 16 + fr + i;
    long col = colBase + wc + ni * 16 + fc;
    out[row * DIMM + col] = acc[mi][ni][i] * OUT_INV + b2[col] + x[row * DIMM + col];
  }
}

extern "C" void kernel_launch(void* const* d_in, const int* in_sizes, int n_in,
                              void* d_out, int out_size, void* d_ws, size_t ws_size,
                              hipStream_t stream) {
  const float* x          = (const float*)d_in[0];
  const float* W1         = (const float*)d_in[1];
  const float* b1         = (const float*)d_in[2];
  const float* W2         = (const float*)d_in[3];
  const float* b2         = (const float*)d_in[4];
  const float* rope_a     = (const float*)d_in[5];
  const float* rope_b     = (const float*)d_in[6];
  const float* gamma      = (const float*)d_in[7];
  const float* beta       = (const float*)d_in[8];
  const float* norm_scale = (const float*)d_in[9];
  float* out = (float*)d_out;

  char* ws = (char*)d_ws;
  size_t off = 0;
  auto nxt = [&](size_t bytes) -> void* {
    void* p = ws + off;
    off += (bytes + 255) & ~(size_t)255;
    return p;
  };
  unsigned short* xn  = (unsigned short*)nxt((size_t)ROWS * DIMM * 2);
  unsigned short* w1t = (unsigned short*)nxt((size_t)PROJ_ * DIMM * 2);
  unsigned char*  w2q = (unsigned char*)nxt((size_t)DIMM * EXP);
  unsigned char*  uq  = (unsigned char*)nxt((size_t)ROWS * EXP);
  unsigned char*  vT  = (unsigned char*)nxt((size_t)NBATCH * EXP * SEQ);
  unsigned char*  qq  = (unsigned char*)nxt((size_t)ROWS * SH);
  unsigned char*  kq  = (unsigned char*)nxt((size_t)ROWS * SH);
  float*          tpl = (float*)nxt((size_t)4096 * 4);
  unsigned char*  ker = (unsigned char*)nxt((size_t)NBATCH * SEQ * SEQ);
  unsigned char*  obq = (unsigned char*)nxt((size_t)ROWS * EXP);

  prep_kernel<<<9791, 256, 0, stream>>>(x, norm_scale, xn, W1, w1t, W2, w2q,
                                        rope_a, rope_b, tpl);
  gemm_uv<<<dim3(ROWS / 128, PROJ_ / 128), 256, 0, stream>>>(xn, w1t, b1, gamma, beta,
                                                             uq, vT, qq, kq);
  gemm_qk<<<2048, 256, 0, stream>>>(qq, kq, tpl, ker);
  gemm_pv<<<1024, 256, 0, stream>>>(ker, vT, uq, obq);
  gemm_out<<<dim3(ROWS / 128, DIMM / 128), 256, 0, stream>>>(obq, w2q, b2, x, out);
}